// Round 4
// baseline (182.481 us; speedup 1.0000x reference)
//
#include <hip/hip_runtime.h>
#include <stdint.h>

// monotone order-preserving float<->uint mapping (works for all signs)
__device__ __forceinline__ uint32_t mapf(float f) {
  uint32_t u = __float_as_uint(f);
  return (u & 0x80000000u) ? ~u : (u | 0x80000000u);
}
__device__ __forceinline__ float unmapf(uint32_t m) {
  return (m & 0x80000000u) ? __uint_as_float(m & 0x7FFFFFFFu) : __uint_as_float(~m);
}

// ---------------- kernel 1: global min/max via mapped-uint atomics,
//                  block 0 also builds byte table + copies small outputs ----------------
// ws dwords: [0]=mapped min  [1]=mapped max  [8..39]=table: 8 x (rlo,rhi,scale,offset)
__global__ __launch_bounds__(256) void k_minmax(const float* __restrict__ x, int n4, int ntail,
                                                const float* __restrict__ co, const float* __restrict__ sfil,
                                                uint32_t* __restrict__ wsu,
                                                float* __restrict__ out_co, float* __restrict__ out_sf) {
  __shared__ float smn[256], smx[256];
  int tid = threadIdx.x;
  float mn = 3.0e38f, mx = -3.0e38f;
  const float4* x4 = (const float4*)x;
  for (int i = blockIdx.x * blockDim.x + tid; i < n4; i += gridDim.x * blockDim.x) {
    float4 v = x4[i];
    mn = fminf(mn, fminf(fminf(v.x, v.y), fminf(v.z, v.w)));
    mx = fmaxf(mx, fmaxf(fmaxf(v.x, v.y), fmaxf(v.z, v.w)));
  }
  if (blockIdx.x == 0 && tid == 0) {
    for (int i = 4 * n4; i < 4 * n4 + ntail; ++i) { mn = fminf(mn, x[i]); mx = fmaxf(mx, x[i]); }
  }
  smn[tid] = mn; smx[tid] = mx;
  __syncthreads();
  for (int s = 128; s > 0; s >>= 1) {
    if (tid < s) { smn[tid] = fminf(smn[tid], smn[tid + s]); smx[tid] = fmaxf(smx[tid], smx[tid + s]); }
    __syncthreads();
  }
  if (tid == 0) {
    atomicMin(&wsu[0], mapf(smn[0]));
    atomicMax(&wsu[1], mapf(smx[0]));
  }
  if (blockIdx.x == 0) {
    if (tid < 8) {   // per-row byte quantization of co_matrix
      const float* r = co + tid * 8;
      float rmn = r[0], rmx = r[0];
      #pragma unroll
      for (int j = 1; j < 8; ++j) { rmn = fminf(rmn, r[j]); rmx = fmaxf(rmx, r[j]); }
      float rs = (rmx - rmn) * (1.0f / 255.0f);
      if (rs < 1e-30f) rs = 1.0f;
      uint32_t d0 = 0, d1 = 0;
      #pragma unroll
      for (int j = 0; j < 8; ++j) {
        int b = (int)lrintf((r[j] - rmn) / rs);
        b = b < 0 ? 0 : (b > 255 ? 255 : b);
        if (j < 4) d0 |= ((uint32_t)b) << (8 * j);
        else       d1 |= ((uint32_t)b) << (8 * (j - 4));
      }
      wsu[8 + 4 * tid + 0] = d0;
      wsu[8 + 4 * tid + 1] = d1;
      wsu[8 + 4 * tid + 2] = __float_as_uint(rs);
      wsu[8 + 4 * tid + 3] = __float_as_uint(rmn);
    }
    if (tid < 64) out_co[tid] = co[tid];
    if (tid < 27) out_sf[tid] = sfil[tid];
  }
}

// ---------------- kernel 2: fused quantize + selected 27-tap stencil ----------------
// tile: 2 c x 8 h x 128 w; 256 threads = 32(w) x 8(h); 4 w-outputs/thread, 2 c-iters
// LDS 26.5 KB -> 6 blocks/CU; target <=85 VGPR for 6 waves/EU
__global__ __launch_bounds__(256) void k_conv(const float* __restrict__ x, const float* __restrict__ sfil,
                                              const uint32_t* __restrict__ wsu,
                                              float* __restrict__ out, float* __restrict__ out_idx) {
  __shared__ __align__(16) float    xs[5280];    // 4 planes x 10 rows x 132
  __shared__ __align__(16) uint32_t qls[1320];   // 4 x 10 x 33 (4 clamped q-bytes per dword)
  __shared__ __align__(16) uint4    tbl[8];      // rlo, rhi, scale, offset per q0

  int tid = threadIdx.x;
  int b = blockIdx.x;
  int wt = b & 1, ht = (b >> 1) & 31, ct = (b >> 6) & 7, n = b >> 9;
  int c0 = ct * 2, h0 = ht * 8, w0 = wt * 128;
  int nbase = n * 16;

  if (tid < 8) tbl[tid] = ((const uint4*)(wsu + 8))[tid];

  float mn = unmapf(wsu[0]);
  float mx = unmapf(wsu[1]);
  float y  = 1.0f / mx;   // correctly-rounded IEEE reciprocal, once per thread

  // ---- staging: 1320 float4-groups of (clean x, clamped q byte) ----
  for (int e = tid; e < 1320; e += 256) {
    int lc = e / 330;
    int r  = e - lc * 330;
    int lh = r / 33;
    int lg = r - lh * 33;
    int c = c0 - 1 + lc, h = h0 - 1 + lh, wb = w0 - 1 + 4 * lg;
    bool chok = ((unsigned)c < 16u) & ((unsigned)h < 256u);
    int gofs = ((nbase + c) << 16) + (h << 8) + wb;
    float xv[4]; uint32_t qu[4];
    #pragma unroll
    for (int j = 0; j < 4; ++j) {
      float xj = 0.0f;
      if (chok & ((unsigned)(wb + j) < 256u)) xj = x[gofs + j];
      // bit-exact d = fl((x-mn)/mx) via Markstein (y correctly rounded, 2 corrections)
      float s  = xj - mn;
      float t0 = s * y;
      float r0 = __builtin_fmaf(-mx, t0, s);
      float t1 = __builtin_fmaf(r0, y, t0);
      float r1 = __builtin_fmaf(-mx, t1, s);
      float d  = __builtin_fmaf(r1, y, t1);
      int q = (int)(d * 8.0f);
      xv[j] = xj;
      qu[j] = (uint32_t)(q > 7 ? 7 : q);   // JAX gather clamps OOB index for tap lookups
    }
    uint32_t b01 = __builtin_amdgcn_perm(qu[1], qu[0], 0x0c0c0400u);
    uint32_t b23 = __builtin_amdgcn_perm(qu[3], qu[2], 0x04000c0cu);
    int ro = lc * 10 + lh;
    *(float4*)&xs[ro * 132 + 4 * lg] = float4{xv[0], xv[1], xv[2], xv[3]};
    qls[ro * 33 + lg] = b01 | b23;
  }
  __syncthreads();

  float wf[27];
  #pragma unroll
  for (int i = 0; i < 27; ++i) wf[i] = sfil[i];   // uniform -> scalar regs

  const int tw = tid & 31, th = tid >> 5;
  const uint32_t SELK[4] = {0x03020100u, 0x04030201u, 0x05040302u, 0x06050403u};

  for (int c = 0; c < 2; ++c) {
    int xbase = (c * 10 + th) * 132 + 4 * tw;
    int qbase = (c * 10 + th) * 33 + tw;

    // center q-bytes (clamped) -> per-output table rows
    int qc = qbase + 11 * 33;
    uint32_t Qc0 = qls[qc], Qc1 = qls[qc + 1];
    uint32_t q4 = __builtin_amdgcn_perm(Qc1, Qc0, 0x04030201u);
    uint32_t rlo[4], rhi[4]; float rs4[4], rc4[4];
    #pragma unroll
    for (int k = 0; k < 4; ++k) {
      uint32_t qk = (q4 >> (8 * k)) & 0xffu;
      uint4 T = tbl[qk];
      rlo[k] = T.x; rhi[k] = T.y;
      rs4[k] = __uint_as_float(T.z); rc4[k] = __uint_as_float(T.w);
    }

    float acc1[4] = {0.f, 0.f, 0.f, 0.f};
    float acc2[4] = {0.f, 0.f, 0.f, 0.f};
    float4 cxA; float2 cxB;   // center-row clean x (captured at dc=1,di=1)
    #pragma unroll
    for (int dc = 0; dc < 3; ++dc) {
      #pragma unroll
      for (int di = 0; di < 3; ++di) {
        int xo = xbase + (dc * 10 + di) * 132;
        float4 A = *(const float4*)&xs[xo];
        float2 B = *(const float2*)&xs[xo + 4];
        if (dc == 1 && di == 1) { cxA = A; cxB = B; }
        int qo = qbase + (dc * 10 + di) * 33;
        uint32_t Q0 = qls[qo], Q1 = qls[qo + 1];
        float xw[6] = {A.x, A.y, A.z, A.w, B.x, B.y};
        const float* wr = &wf[dc * 9 + di * 3];
        #pragma unroll
        for (int k = 0; k < 4; ++k) {
          uint32_t sel = __builtin_amdgcn_perm(Q1, Q0, SELK[k]);     // 3 q-bytes
          uint32_t bb  = __builtin_amdgcn_perm(rhi[k], rlo[k], sel); // 3 table bytes
          float b0 = (float)(bb & 0xffu);          // v_cvt_f32_ubyte0
          float b1 = (float)((bb >> 8) & 0xffu);   // v_cvt_f32_ubyte1
          float b2 = (float)((bb >> 16) & 0xffu);  // v_cvt_f32_ubyte2
          float p0 = wr[0] * xw[k];
          float p1 = wr[1] * xw[k + 1];
          float p2 = wr[2] * xw[k + 2];
          acc2[k] += p0 + p1 + p2;
          acc1[k] = __builtin_fmaf(p0, b0, acc1[k]);
          acc1[k] = __builtin_fmaf(p1, b1, acc1[k]);
          acc1[k] = __builtin_fmaf(p2, b2, acc1[k]);
        }
      }
    }

    // recompute exact unclamped q for the 4 center elements (for idx out + q==8 mask)
    float cx[4] = {cxA.y, cxA.z, cxA.w, cxB.x};
    int qt[4];
    #pragma unroll
    for (int k = 0; k < 4; ++k) {
      float s  = cx[k] - mn;
      float t0 = s * y;
      float r0 = __builtin_fmaf(-mx, t0, s);
      float t1 = __builtin_fmaf(r0, y, t0);
      float r1 = __builtin_fmaf(-mx, t1, s);
      float d  = __builtin_fmaf(r1, y, t1);
      qt[k] = (int)(d * 8.0f);
    }

    int gbase = ((nbase + c0 + c) << 16) + ((h0 + th) << 8) + (w0 + 4 * tw);
    float4 o;
    o.x = qt[0] > 7 ? 0.0f : __builtin_fmaf(rs4[0], acc1[0], rc4[0] * acc2[0]);
    o.y = qt[1] > 7 ? 0.0f : __builtin_fmaf(rs4[1], acc1[1], rc4[1] * acc2[1]);
    o.z = qt[2] > 7 ? 0.0f : __builtin_fmaf(rs4[2], acc1[2], rc4[2] * acc2[2]);
    o.w = qt[3] > 7 ? 0.0f : __builtin_fmaf(rs4[3], acc1[3], rc4[3] * acc2[3]);
    *(float4*)&out[gbase] = o;
    out_idx[gbase + 0] = (float)qt[0];
    out_idx[gbase + 1] = (float)qt[1];
    out_idx[gbase + 2] = (float)qt[2];
    out_idx[gbase + 3] = (float)qt[3];
  }
}

extern "C" void kernel_launch(void* const* d_in, const int* in_sizes, int n_in,
                              void* d_out, int out_size, void* d_ws, size_t ws_size,
                              hipStream_t stream) {
  const float* x    = (const float*)d_in[0];
  const float* co   = (const float*)d_in[1];
  const float* sfil = (const float*)d_in[2];
  float* out = (float*)d_out;
  uint32_t* wsu = (uint32_t*)d_ws;
  int nx = in_sizes[0];  // 8*16*256*256

  int n4 = nx / 4, ntail = nx - 4 * n4;

  float* out_co  = out + nx;
  float* out_sf  = out + nx + 64;
  float* out_idx = out + nx + 64 + 27;

  // init mapped-uint min (all-ones = +inf side) and max (zero = -inf side)
  hipMemsetAsync(wsu + 0, 0xFF, 4, stream);
  hipMemsetAsync(wsu + 1, 0x00, 4, stream);

  k_minmax<<<2048, 256, 0, stream>>>(x, n4, ntail, co, sfil, wsu, out_co, out_sf);
  k_conv<<<4096, 256, 0, stream>>>(x, sfil, wsu, out, out_idx);
}

// Round 5
// 139.871 us; speedup vs baseline: 1.3046x; 1.3046x over previous
//
#include <hip/hip_runtime.h>
#include <stdint.h>

// monotone order-preserving float<->uint mapping (works for all signs)
__device__ __forceinline__ uint32_t mapf(float f) {
  uint32_t u = __float_as_uint(f);
  return (u & 0x80000000u) ? ~u : (u | 0x80000000u);
}
__device__ __forceinline__ float unmapf(uint32_t m) {
  return (m & 0x80000000u) ? __uint_as_float(m & 0x7FFFFFFFu) : __uint_as_float(~m);
}

// ws dwords: [8..39]=table: 8 x (rlo,rhi,scale,offset)
//            [64..79]=slotA (mapped max, 16-way spread)  [80..95]=slotB (mapped -min)
// slots zero-initialized by one 128-B memset; reduced with atomicMax only.

// ---------------- kernel 1: global min/max (spread atomics),
//                  block 0 also builds byte table + copies small outputs ----------------
__global__ __launch_bounds__(256) void k_minmax(const float* __restrict__ x, int n4, int ntail,
                                                const float* __restrict__ co, const float* __restrict__ sfil,
                                                uint32_t* __restrict__ wsu,
                                                float* __restrict__ out_co, float* __restrict__ out_sf) {
  __shared__ float smn[256], smx[256];
  int tid = threadIdx.x;
  float mn = 3.0e38f, mx = -3.0e38f;
  const float4* x4 = (const float4*)x;
  int stride = gridDim.x * blockDim.x;
  #pragma unroll 4
  for (int i = blockIdx.x * blockDim.x + tid; i < n4; i += stride) {
    float4 v = x4[i];
    mn = fminf(mn, fminf(fminf(v.x, v.y), fminf(v.z, v.w)));
    mx = fmaxf(mx, fmaxf(fmaxf(v.x, v.y), fmaxf(v.z, v.w)));
  }
  if (blockIdx.x == 0 && tid == 0) {
    for (int i = 4 * n4; i < 4 * n4 + ntail; ++i) { mn = fminf(mn, x[i]); mx = fmaxf(mx, x[i]); }
  }
  smn[tid] = mn; smx[tid] = mx;
  __syncthreads();
  for (int s = 128; s > 0; s >>= 1) {
    if (tid < s) { smn[tid] = fminf(smn[tid], smn[tid + s]); smx[tid] = fmaxf(smx[tid], smx[tid + s]); }
    __syncthreads();
  }
  if (tid == 0) {
    int slot = blockIdx.x & 15;
    atomicMax(&wsu[64 + slot], mapf(smx[0]));    // max
    atomicMax(&wsu[80 + slot], mapf(-smn[0]));   // min via max of negation (exact)
  }
  if (blockIdx.x == 0) {
    if (tid < 8) {   // per-row byte quantization of co_matrix
      const float* r = co + tid * 8;
      float rmn = r[0], rmx = r[0];
      #pragma unroll
      for (int j = 1; j < 8; ++j) { rmn = fminf(rmn, r[j]); rmx = fmaxf(rmx, r[j]); }
      float rs = (rmx - rmn) * (1.0f / 255.0f);
      if (rs < 1e-30f) rs = 1.0f;
      uint32_t d0 = 0, d1 = 0;
      #pragma unroll
      for (int j = 0; j < 8; ++j) {
        int b = (int)lrintf((r[j] - rmn) / rs);
        b = b < 0 ? 0 : (b > 255 ? 255 : b);
        if (j < 4) d0 |= ((uint32_t)b) << (8 * j);
        else       d1 |= ((uint32_t)b) << (8 * (j - 4));
      }
      wsu[8 + 4 * tid + 0] = d0;
      wsu[8 + 4 * tid + 1] = d1;
      wsu[8 + 4 * tid + 2] = __float_as_uint(rs);
      wsu[8 + 4 * tid + 3] = __float_as_uint(rmn);
    }
    if (tid < 64) out_co[tid] = co[tid];
    if (tid < 27) out_sf[tid] = sfil[tid];
  }
}

// ---------------- kernel 2: fused quantize + selected 27-tap stencil ----------------
// tile: 2 c x 8 h x 128 w; 256 threads = 32(w) x 8(h); 4 w-outputs/thread, 2 c-iters
__global__ __launch_bounds__(256) void k_conv(const float* __restrict__ x, const float* __restrict__ sfil,
                                              const uint32_t* __restrict__ wsu,
                                              float* __restrict__ out, float* __restrict__ out_idx) {
  __shared__ __align__(16) float    xs[5280];    // 4 planes x 10 rows x 132
  __shared__ __align__(16) uint32_t qls[1320];   // 4 x 10 x 33 (4 clamped q-bytes per dword)
  __shared__ __align__(16) uint4    tbl[8];      // rlo, rhi, scale, offset per q0

  int tid = threadIdx.x;
  int b = blockIdx.x;
  int wt = b & 1, ht = (b >> 1) & 31, ct = (b >> 6) & 7, n = b >> 9;
  int c0 = ct * 2, h0 = ht * 8, w0 = wt * 128;
  int nbase = n * 16;

  if (tid < 8) tbl[tid] = ((const uint4*)(wsu + 8))[tid];

  // reduce the 16+16 spread slots (uniform scalar loads)
  uint32_t ma = 0u, mb = 0u;
  #pragma unroll
  for (int i = 0; i < 16; ++i) {
    uint32_t a = wsu[64 + i], bq = wsu[80 + i];
    ma = ma > a ? ma : a;
    mb = mb > bq ? mb : bq;
  }
  float mx = unmapf(ma);
  float mn = -unmapf(mb);
  float y  = 1.0f / mx;   // correctly-rounded IEEE reciprocal

  // ---- staging: 1320 float4-groups of (clean x, clamped q byte) ----
  for (int e = tid; e < 1320; e += 256) {
    int lc = e / 330;
    int r  = e - lc * 330;
    int lh = r / 33;
    int lg = r - lh * 33;
    int c = c0 - 1 + lc, h = h0 - 1 + lh, wb = w0 - 1 + 4 * lg;
    bool chok = ((unsigned)c < 16u) & ((unsigned)h < 256u);
    int gofs = ((nbase + c) << 16) + (h << 8) + wb;
    float xv[4]; uint32_t qu[4];
    #pragma unroll
    for (int j = 0; j < 4; ++j) {
      float xj = 0.0f;
      if (chok & ((unsigned)(wb + j) < 256u)) xj = x[gofs + j];
      // bit-exact d = fl((x-mn)/mx) via Markstein (y correctly rounded, 2 corrections)
      float s  = xj - mn;
      float t0 = s * y;
      float r0 = __builtin_fmaf(-mx, t0, s);
      float t1 = __builtin_fmaf(r0, y, t0);
      float r1 = __builtin_fmaf(-mx, t1, s);
      float d  = __builtin_fmaf(r1, y, t1);
      int q = (int)(d * 8.0f);
      xv[j] = xj;
      qu[j] = (uint32_t)(q > 7 ? 7 : q);   // JAX gather clamps OOB index for tap lookups
    }
    uint32_t b01 = __builtin_amdgcn_perm(qu[1], qu[0], 0x0c0c0400u);
    uint32_t b23 = __builtin_amdgcn_perm(qu[3], qu[2], 0x04000c0cu);
    int ro = lc * 10 + lh;
    *(float4*)&xs[ro * 132 + 4 * lg] = float4{xv[0], xv[1], xv[2], xv[3]};
    qls[ro * 33 + lg] = b01 | b23;
  }
  __syncthreads();

  float wf[27];
  #pragma unroll
  for (int i = 0; i < 27; ++i) wf[i] = sfil[i];   // uniform -> scalar regs

  const int tw = tid & 31, th = tid >> 5;
  const uint32_t SELK[4] = {0x03020100u, 0x04030201u, 0x05040302u, 0x06050403u};

  for (int c = 0; c < 2; ++c) {
    int xbase = (c * 10 + th) * 132 + 4 * tw;
    int qbase = (c * 10 + th) * 33 + tw;

    // center q-bytes (clamped) -> per-output table rows
    int qc = qbase + 11 * 33;
    uint32_t Qc0 = qls[qc], Qc1 = qls[qc + 1];
    uint32_t q4 = __builtin_amdgcn_perm(Qc1, Qc0, 0x04030201u);
    uint32_t rlo[4], rhi[4]; float rs4[4], rc4[4];
    #pragma unroll
    for (int k = 0; k < 4; ++k) {
      uint32_t qk = (q4 >> (8 * k)) & 0xffu;
      uint4 T = tbl[qk];
      rlo[k] = T.x; rhi[k] = T.y;
      rs4[k] = __uint_as_float(T.z); rc4[k] = __uint_as_float(T.w);
    }

    float acc1[4] = {0.f, 0.f, 0.f, 0.f};
    float acc2[4] = {0.f, 0.f, 0.f, 0.f};
    float4 cxA; float2 cxB;   // center-row clean x (captured at dc=1,di=1)
    #pragma unroll
    for (int dc = 0; dc < 3; ++dc) {
      #pragma unroll
      for (int di = 0; di < 3; ++di) {
        int xo = xbase + (dc * 10 + di) * 132;
        float4 A = *(const float4*)&xs[xo];
        float2 B = *(const float2*)&xs[xo + 4];
        if (dc == 1 && di == 1) { cxA = A; cxB = B; }
        int qo = qbase + (dc * 10 + di) * 33;
        uint32_t Q0 = qls[qo], Q1 = qls[qo + 1];
        float xw[6] = {A.x, A.y, A.z, A.w, B.x, B.y};
        const float* wr = &wf[dc * 9 + di * 3];
        #pragma unroll
        for (int k = 0; k < 4; ++k) {
          uint32_t sel = __builtin_amdgcn_perm(Q1, Q0, SELK[k]);     // 3 q-bytes
          uint32_t bb  = __builtin_amdgcn_perm(rhi[k], rlo[k], sel); // 3 table bytes
          float b0 = (float)(bb & 0xffu);          // v_cvt_f32_ubyte0
          float b1 = (float)((bb >> 8) & 0xffu);   // v_cvt_f32_ubyte1
          float b2 = (float)((bb >> 16) & 0xffu);  // v_cvt_f32_ubyte2
          float p0 = wr[0] * xw[k];
          float p1 = wr[1] * xw[k + 1];
          float p2 = wr[2] * xw[k + 2];
          acc2[k] += p0 + p1 + p2;
          acc1[k] = __builtin_fmaf(p0, b0, acc1[k]);
          acc1[k] = __builtin_fmaf(p1, b1, acc1[k]);
          acc1[k] = __builtin_fmaf(p2, b2, acc1[k]);
        }
      }
    }

    // recompute exact unclamped q for the 4 center elements (for idx out + q==8 mask)
    float cx[4] = {cxA.y, cxA.z, cxA.w, cxB.x};
    int qt[4];
    #pragma unroll
    for (int k = 0; k < 4; ++k) {
      float s  = cx[k] - mn;
      float t0 = s * y;
      float r0 = __builtin_fmaf(-mx, t0, s);
      float t1 = __builtin_fmaf(r0, y, t0);
      float r1 = __builtin_fmaf(-mx, t1, s);
      float d  = __builtin_fmaf(r1, y, t1);
      qt[k] = (int)(d * 8.0f);
    }

    int gbase = ((nbase + c0 + c) << 16) + ((h0 + th) << 8) + (w0 + 4 * tw);
    float4 o;
    o.x = qt[0] > 7 ? 0.0f : __builtin_fmaf(rs4[0], acc1[0], rc4[0] * acc2[0]);
    o.y = qt[1] > 7 ? 0.0f : __builtin_fmaf(rs4[1], acc1[1], rc4[1] * acc2[1]);
    o.z = qt[2] > 7 ? 0.0f : __builtin_fmaf(rs4[2], acc1[2], rc4[2] * acc2[2]);
    o.w = qt[3] > 7 ? 0.0f : __builtin_fmaf(rs4[3], acc1[3], rc4[3] * acc2[3]);
    *(float4*)&out[gbase] = o;
    out_idx[gbase + 0] = (float)qt[0];
    out_idx[gbase + 1] = (float)qt[1];
    out_idx[gbase + 2] = (float)qt[2];
    out_idx[gbase + 3] = (float)qt[3];
  }
}

extern "C" void kernel_launch(void* const* d_in, const int* in_sizes, int n_in,
                              void* d_out, int out_size, void* d_ws, size_t ws_size,
                              hipStream_t stream) {
  const float* x    = (const float*)d_in[0];
  const float* co   = (const float*)d_in[1];
  const float* sfil = (const float*)d_in[2];
  float* out = (float*)d_out;
  uint32_t* wsu = (uint32_t*)d_ws;
  int nx = in_sizes[0];  // 8*16*256*256

  int n4 = nx / 4, ntail = nx - 4 * n4;

  float* out_co  = out + nx;
  float* out_sf  = out + nx + 64;
  float* out_idx = out + nx + 64 + 27;

  // zero the 32 spread atomic-max slots (one 128-B memset node)
  hipMemsetAsync(wsu + 64, 0, 128, stream);

  k_minmax<<<512, 256, 0, stream>>>(x, n4, ntail, co, sfil, wsu, out_co, out_sf);
  k_conv<<<4096, 256, 0, stream>>>(x, sfil, wsu, out, out_idx);
}

// Round 6
// 138.518 us; speedup vs baseline: 1.3174x; 1.0098x over previous
//
#include <hip/hip_runtime.h>
#include <stdint.h>

typedef float v2f __attribute__((ext_vector_type(2)));

// monotone order-preserving float<->uint mapping (works for all signs)
__device__ __forceinline__ uint32_t mapf(float f) {
  uint32_t u = __float_as_uint(f);
  return (u & 0x80000000u) ? ~u : (u | 0x80000000u);
}
__device__ __forceinline__ float unmapf(uint32_t m) {
  return (m & 0x80000000u) ? __uint_as_float(m & 0x7FFFFFFFu) : __uint_as_float(~m);
}

// ws dwords: [8..39]=table: 8 x (rlo,rhi,scale,offset)
//            [64..79]=slotA (mapped max, 16-way spread)  [80..95]=slotB (mapped -min)

// ---------------- kernel 1: global min/max (spread atomics),
//                  block 0 also builds byte table + copies small outputs ----------------
__global__ __launch_bounds__(256) void k_minmax(const float* __restrict__ x, int n4, int ntail,
                                                const float* __restrict__ co, const float* __restrict__ sfil,
                                                uint32_t* __restrict__ wsu,
                                                float* __restrict__ out_co, float* __restrict__ out_sf) {
  __shared__ float smn[256], smx[256];
  int tid = threadIdx.x;
  float mn = 3.0e38f, mx = -3.0e38f;
  const float4* x4 = (const float4*)x;
  int stride = gridDim.x * blockDim.x;
  #pragma unroll 4
  for (int i = blockIdx.x * blockDim.x + tid; i < n4; i += stride) {
    float4 v = x4[i];
    mn = fminf(mn, fminf(fminf(v.x, v.y), fminf(v.z, v.w)));
    mx = fmaxf(mx, fmaxf(fmaxf(v.x, v.y), fmaxf(v.z, v.w)));
  }
  if (blockIdx.x == 0 && tid == 0) {
    for (int i = 4 * n4; i < 4 * n4 + ntail; ++i) { mn = fminf(mn, x[i]); mx = fmaxf(mx, x[i]); }
  }
  smn[tid] = mn; smx[tid] = mx;
  __syncthreads();
  for (int s = 128; s > 0; s >>= 1) {
    if (tid < s) { smn[tid] = fminf(smn[tid], smn[tid + s]); smx[tid] = fmaxf(smx[tid], smx[tid + s]); }
    __syncthreads();
  }
  if (tid == 0) {
    int slot = blockIdx.x & 15;
    atomicMax(&wsu[64 + slot], mapf(smx[0]));    // max
    atomicMax(&wsu[80 + slot], mapf(-smn[0]));   // min via max of negation (exact)
  }
  if (blockIdx.x == 0) {
    if (tid < 8) {   // per-row byte quantization of co_matrix
      const float* r = co + tid * 8;
      float rmn = r[0], rmx = r[0];
      #pragma unroll
      for (int j = 1; j < 8; ++j) { rmn = fminf(rmn, r[j]); rmx = fmaxf(rmx, r[j]); }
      float rs = (rmx - rmn) * (1.0f / 255.0f);
      if (rs < 1e-30f) rs = 1.0f;
      uint32_t d0 = 0, d1 = 0;
      #pragma unroll
      for (int j = 0; j < 8; ++j) {
        int b = (int)lrintf((r[j] - rmn) / rs);
        b = b < 0 ? 0 : (b > 255 ? 255 : b);
        if (j < 4) d0 |= ((uint32_t)b) << (8 * j);
        else       d1 |= ((uint32_t)b) << (8 * (j - 4));
      }
      wsu[8 + 4 * tid + 0] = d0;
      wsu[8 + 4 * tid + 1] = d1;
      wsu[8 + 4 * tid + 2] = __float_as_uint(rs);
      wsu[8 + 4 * tid + 3] = __float_as_uint(rmn);
    }
    if (tid < 64) out_co[tid] = co[tid];
    if (tid < 27) out_sf[tid] = sfil[tid];
  }
}

// ---------------- kernel 2: fused quantize + selected 27-tap stencil ----------------
// tile: 2 c x 8 h x 128 w; 256 threads = 32(w) x 8(h); 4 w-outputs/thread, 2 c-iters
__global__ __launch_bounds__(256) void k_conv(const float* __restrict__ x, const float* __restrict__ sfil,
                                              const uint32_t* __restrict__ wsu,
                                              float* __restrict__ out, float* __restrict__ out_idx) {
  __shared__ __align__(16) float    xs[5280];    // 4 planes x 10 rows x 132
  __shared__ __align__(16) uint32_t qls[1320];   // 4 x 10 x 33 (4 clamped q-bytes per dword)
  __shared__ __align__(16) uint4    tbl[8];      // rlo, rhi, scale, offset per q0

  int tid = threadIdx.x;
  int b = blockIdx.x;
  int wt = b & 1, ht = (b >> 1) & 31, ct = (b >> 6) & 7, n = b >> 9;
  int c0 = ct * 2, h0 = ht * 8, w0 = wt * 128;
  int nbase = n * 16;

  if (tid < 8) tbl[tid] = ((const uint4*)(wsu + 8))[tid];

  // reduce the 16+16 spread slots (uniform scalar loads)
  uint32_t ma = 0u, mb = 0u;
  #pragma unroll
  for (int i = 0; i < 16; ++i) {
    uint32_t a = wsu[64 + i], bq = wsu[80 + i];
    ma = ma > a ? ma : a;
    mb = mb > bq ? mb : bq;
  }
  float mx = unmapf(ma);
  float mn = -unmapf(mb);
  float y  = 1.0f / mx;   // correctly-rounded IEEE reciprocal

  // ---- staging: 1320 float4-groups of (clean x, clamped q byte); Markstein pk'd in pairs ----
  for (int e = tid; e < 1320; e += 256) {
    int lc = e / 330;
    int r  = e - lc * 330;
    int lh = r / 33;
    int lg = r - lh * 33;
    int c = c0 - 1 + lc, h = h0 - 1 + lh, wb = w0 - 1 + 4 * lg;
    bool chok = ((unsigned)c < 16u) & ((unsigned)h < 256u);
    int gofs = ((nbase + c) << 16) + (h << 8) + wb;
    float xv[4];
    #pragma unroll
    for (int j = 0; j < 4; ++j) {
      float xj = 0.0f;
      if (chok & ((unsigned)(wb + j) < 256u)) xj = x[gofs + j];
      xv[j] = xj;
    }
    // bit-exact d = fl((x-mn)/mx) via Markstein (y correctly rounded, 2 corrections), packed
    uint32_t qu[4];
    #pragma unroll
    for (int p = 0; p < 2; ++p) {
      v2f xp; xp.x = xv[2 * p]; xp.y = xv[2 * p + 1];
      v2f s  = xp - mn;
      v2f t0 = s * y;
      v2f r0 = __builtin_elementwise_fma(t0, v2f{-mx, -mx}, s);
      v2f t1 = __builtin_elementwise_fma(r0, v2f{y, y}, t0);
      v2f r1 = __builtin_elementwise_fma(t1, v2f{-mx, -mx}, s);
      v2f d  = __builtin_elementwise_fma(r1, v2f{y, y}, t1);
      v2f d8 = d * 8.0f;
      int qa = (int)d8.x, qb = (int)d8.y;
      qu[2 * p]     = (uint32_t)(qa > 7 ? 7 : qa);   // JAX gather clamps OOB index
      qu[2 * p + 1] = (uint32_t)(qb > 7 ? 7 : qb);
    }
    uint32_t b01 = __builtin_amdgcn_perm(qu[1], qu[0], 0x0c0c0400u);
    uint32_t b23 = __builtin_amdgcn_perm(qu[3], qu[2], 0x04000c0cu);
    int ro = lc * 10 + lh;
    *(float4*)&xs[ro * 132 + 4 * lg] = float4{xv[0], xv[1], xv[2], xv[3]};
    qls[ro * 33 + lg] = b01 | b23;
  }
  __syncthreads();

  float wf[27];
  #pragma unroll
  for (int i = 0; i < 27; ++i) wf[i] = sfil[i];   // uniform -> scalar regs

  const int tw = tid & 31, th = tid >> 5;
  const uint32_t SELK[4] = {0x03020100u, 0x04030201u, 0x05040302u, 0x06050403u};

  for (int c = 0; c < 2; ++c) {
    int xbase = (c * 10 + th) * 132 + 4 * tw;
    int qbase = (c * 10 + th) * 33 + tw;

    // center q-bytes (clamped) -> per-output table rows
    int qc = qbase + 11 * 33;
    uint32_t Qc0 = qls[qc], Qc1 = qls[qc + 1];
    uint32_t q4 = __builtin_amdgcn_perm(Qc1, Qc0, 0x04030201u);
    uint32_t rlo[4], rhi[4]; float rs4[4], rc4[4];
    #pragma unroll
    for (int k = 0; k < 4; ++k) {
      uint32_t qk = (q4 >> (8 * k)) & 0xffu;
      uint4 T = tbl[qk];
      rlo[k] = T.x; rhi[k] = T.y;
      rs4[k] = __uint_as_float(T.z); rc4[k] = __uint_as_float(T.w);
    }

    v2f acc1p[2] = {v2f{0.f, 0.f}, v2f{0.f, 0.f}};
    v2f acc2p[2] = {v2f{0.f, 0.f}, v2f{0.f, 0.f}};
    float4 cxA; float2 cxB;   // center-row clean x (captured at dc=1,di=1)
    #pragma unroll
    for (int dc = 0; dc < 3; ++dc) {
      #pragma unroll
      for (int di = 0; di < 3; ++di) {
        int xo = xbase + (dc * 10 + di) * 132;
        float4 A = *(const float4*)&xs[xo];
        float2 B = *(const float2*)&xs[xo + 4];
        if (dc == 1 && di == 1) { cxA = A; cxB = B; }
        int qo = qbase + (dc * 10 + di) * 33;
        uint32_t Q0 = qls[qo], Q1 = qls[qo + 1];
        const float* wr = &wf[dc * 9 + di * 3];
        // aligned x pairs from the vector loads + two 1-instr shuffles
        v2f P0; P0.x = A.x; P0.y = A.y;    // (x0,x1)
        v2f P1; P1.x = A.z; P1.y = A.w;    // (x2,x3)
        v2f P2; P2.x = B.x; P2.y = B.y;    // (x4,x5)
        v2f M01; M01.x = A.y; M01.y = A.z; // (x1,x2)
        v2f M34; M34.x = A.w; M34.y = B.x; // (x3,x4)
        #pragma unroll
        for (int K = 0; K < 2; ++K) {      // output pairs (0,1) and (2,3)
          int k0 = 2 * K;
          uint32_t selA = __builtin_amdgcn_perm(Q1, Q0, SELK[k0]);
          uint32_t bbA  = __builtin_amdgcn_perm(rhi[k0], rlo[k0], selA);
          uint32_t selB = __builtin_amdgcn_perm(Q1, Q0, SELK[k0 + 1]);
          uint32_t bbB  = __builtin_amdgcn_perm(rhi[k0 + 1], rlo[k0 + 1], selB);
          v2f b0; b0.x = (float)(bbA & 0xffu);         b0.y = (float)(bbB & 0xffu);
          v2f b1; b1.x = (float)((bbA >> 8) & 0xffu);  b1.y = (float)((bbB >> 8) & 0xffu);
          v2f b2; b2.x = (float)((bbA >> 16) & 0xffu); b2.y = (float)((bbB >> 16) & 0xffu);
          v2f X0 = (K == 0) ? P0 : P1;
          v2f X1 = (K == 0) ? M01 : M34;
          v2f X2 = (K == 0) ? P1 : P2;
          v2f p0 = X0 * wr[0];             // v_pk_mul_f32
          v2f p1 = X1 * wr[1];
          v2f p2 = X2 * wr[2];
          acc2p[K] += p0 + p1 + p2;        // v_pk_add_f32
          acc1p[K] = __builtin_elementwise_fma(p0, b0, acc1p[K]);  // v_pk_fma_f32
          acc1p[K] = __builtin_elementwise_fma(p1, b1, acc1p[K]);
          acc1p[K] = __builtin_elementwise_fma(p2, b2, acc1p[K]);
        }
      }
    }

    // recompute exact unclamped q for the 4 center elements (for idx out + q==8 mask)
    float cx[4] = {cxA.y, cxA.z, cxA.w, cxB.x};
    int qt[4];
    #pragma unroll
    for (int k = 0; k < 4; ++k) {
      float s  = cx[k] - mn;
      float t0 = s * y;
      float r0 = __builtin_fmaf(-mx, t0, s);
      float t1 = __builtin_fmaf(r0, y, t0);
      float r1 = __builtin_fmaf(-mx, t1, s);
      float d  = __builtin_fmaf(r1, y, t1);
      qt[k] = (int)(d * 8.0f);
    }

    int gbase = ((nbase + c0 + c) << 16) + ((h0 + th) << 8) + (w0 + 4 * tw);
    float4 o;
    o.x = qt[0] > 7 ? 0.0f : __builtin_fmaf(rs4[0], acc1p[0].x, rc4[0] * acc2p[0].x);
    o.y = qt[1] > 7 ? 0.0f : __builtin_fmaf(rs4[1], acc1p[0].y, rc4[1] * acc2p[0].y);
    o.z = qt[2] > 7 ? 0.0f : __builtin_fmaf(rs4[2], acc1p[1].x, rc4[2] * acc2p[1].x);
    o.w = qt[3] > 7 ? 0.0f : __builtin_fmaf(rs4[3], acc1p[1].y, rc4[3] * acc2p[1].y);
    *(float4*)&out[gbase] = o;
    out_idx[gbase + 0] = (float)qt[0];
    out_idx[gbase + 1] = (float)qt[1];
    out_idx[gbase + 2] = (float)qt[2];
    out_idx[gbase + 3] = (float)qt[3];
  }
}

extern "C" void kernel_launch(void* const* d_in, const int* in_sizes, int n_in,
                              void* d_out, int out_size, void* d_ws, size_t ws_size,
                              hipStream_t stream) {
  const float* x    = (const float*)d_in[0];
  const float* co   = (const float*)d_in[1];
  const float* sfil = (const float*)d_in[2];
  float* out = (float*)d_out;
  uint32_t* wsu = (uint32_t*)d_ws;
  int nx = in_sizes[0];  // 8*16*256*256

  int n4 = nx / 4, ntail = nx - 4 * n4;

  float* out_co  = out + nx;
  float* out_sf  = out + nx + 64;
  float* out_idx = out + nx + 64 + 27;

  // zero the 32 spread atomic-max slots (one 128-B memset node)
  hipMemsetAsync(wsu + 64, 0, 128, stream);

  k_minmax<<<512, 256, 0, stream>>>(x, n4, ntail, co, sfil, wsu, out_co, out_sf);
  k_conv<<<4096, 256, 0, stream>>>(x, sfil, wsu, out, out_idx);
}

// Round 7
// 136.462 us; speedup vs baseline: 1.3372x; 1.0151x over previous
//
#include <hip/hip_runtime.h>
#include <stdint.h>

// monotone order-preserving float<->uint mapping (works for all signs)
__device__ __forceinline__ uint32_t mapf(float f) {
  uint32_t u = __float_as_uint(f);
  return (u & 0x80000000u) ? ~u : (u | 0x80000000u);
}
__device__ __forceinline__ float unmapf(uint32_t m) {
  return (m & 0x80000000u) ? __uint_as_float(m & 0x7FFFFFFFu) : __uint_as_float(~m);
}

// ws dwords: [8..39]=table: 8 x (rlo,rhi,scale,offset)
//            [64..79]=slotA (mapped max, 16-way spread)  [80..95]=slotB (mapped -min)

// ---------------- kernel 1: global min/max (spread atomics),
//                  block 0 also builds byte table + copies small outputs ----------------
__global__ __launch_bounds__(256) void k_minmax(const float* __restrict__ x, int n4, int ntail,
                                                const float* __restrict__ co, const float* __restrict__ sfil,
                                                uint32_t* __restrict__ wsu,
                                                float* __restrict__ out_co, float* __restrict__ out_sf) {
  __shared__ float smn[256], smx[256];
  int tid = threadIdx.x;
  float mn = 3.0e38f, mx = -3.0e38f;
  const float4* x4 = (const float4*)x;
  int stride = gridDim.x * blockDim.x;
  #pragma unroll 4
  for (int i = blockIdx.x * blockDim.x + tid; i < n4; i += stride) {
    float4 v = x4[i];
    mn = fminf(mn, fminf(fminf(v.x, v.y), fminf(v.z, v.w)));
    mx = fmaxf(mx, fmaxf(fmaxf(v.x, v.y), fmaxf(v.z, v.w)));
  }
  if (blockIdx.x == 0 && tid == 0) {
    for (int i = 4 * n4; i < 4 * n4 + ntail; ++i) { mn = fminf(mn, x[i]); mx = fmaxf(mx, x[i]); }
  }
  smn[tid] = mn; smx[tid] = mx;
  __syncthreads();
  for (int s = 128; s > 0; s >>= 1) {
    if (tid < s) { smn[tid] = fminf(smn[tid], smn[tid + s]); smx[tid] = fmaxf(smx[tid], smx[tid + s]); }
    __syncthreads();
  }
  if (tid == 0) {
    int slot = blockIdx.x & 15;
    atomicMax(&wsu[64 + slot], mapf(smx[0]));    // max
    atomicMax(&wsu[80 + slot], mapf(-smn[0]));   // min via max of negation (exact)
  }
  if (blockIdx.x == 0) {
    if (tid < 8) {   // per-row byte quantization of co_matrix
      const float* r = co + tid * 8;
      float rmn = r[0], rmx = r[0];
      #pragma unroll
      for (int j = 1; j < 8; ++j) { rmn = fminf(rmn, r[j]); rmx = fmaxf(rmx, r[j]); }
      float rs = (rmx - rmn) * (1.0f / 255.0f);
      if (rs < 1e-30f) rs = 1.0f;
      uint32_t d0 = 0, d1 = 0;
      #pragma unroll
      for (int j = 0; j < 8; ++j) {
        int b = (int)lrintf((r[j] - rmn) / rs);
        b = b < 0 ? 0 : (b > 255 ? 255 : b);
        if (j < 4) d0 |= ((uint32_t)b) << (8 * j);
        else       d1 |= ((uint32_t)b) << (8 * (j - 4));
      }
      wsu[8 + 4 * tid + 0] = d0;
      wsu[8 + 4 * tid + 1] = d1;
      wsu[8 + 4 * tid + 2] = __float_as_uint(rs);
      wsu[8 + 4 * tid + 3] = __float_as_uint(rmn);
    }
    if (tid < 64) out_co[tid] = co[tid];
    if (tid < 27) out_sf[tid] = sfil[tid];
  }
}

// 1-step Markstein: d = RN((xv-mn)/mx), given y = RN(1/mx) and fma. Then q = trunc(d*8).
__device__ __forceinline__ int quant_q(float xv, float mn, float mx, float y) {
  float s  = xv - mn;
  float t0 = s * y;
  float r0 = __builtin_fmaf(-mx, t0, s);
  float d  = __builtin_fmaf(r0, y, t0);
  return (int)(d * 8.0f);
}

// ---------------- kernel 2: fused quantize + selected 27-tap stencil ----------------
// tile: 2 c x 8 h x 128 w; 256 threads = 32(w) x 8(h); 4 w-outputs/thread, 2 c-iters
// LDS 26.6 KB -> 6 blocks/CU
__global__ __launch_bounds__(256) void k_conv(const float* __restrict__ x, const float* __restrict__ sfil,
                                              const uint32_t* __restrict__ wsu,
                                              float* __restrict__ out, float* __restrict__ out_idx) {
  __shared__ __align__(16) float    xs[5280];    // 4 planes x 10 rows x 132
  __shared__ __align__(16) uint32_t qls[1320];   // 4 x 10 x 33 (4 clamped q-bytes per dword)
  __shared__ __align__(16) uint4    tbl[8];      // rlo, rhi, scale, offset per q0

  int tid = threadIdx.x;
  int b = blockIdx.x;
  int wt = b & 1, ht = (b >> 1) & 31, ct = (b >> 6) & 7, n = b >> 9;
  int c0 = ct * 2, h0 = ht * 8, w0 = wt * 128;
  int nbase = n * 16;

  if (tid < 8) tbl[tid] = ((const uint4*)(wsu + 8))[tid];

  // reduce the 16+16 spread slots (uniform scalar loads)
  uint32_t ma = 0u, mb = 0u;
  #pragma unroll
  for (int i = 0; i < 16; ++i) {
    uint32_t a = wsu[64 + i], bq = wsu[80 + i];
    ma = ma > a ? ma : a;
    mb = mb > bq ? mb : mb > bq ? mb : bq;
  }
  float mx = unmapf(ma);
  float mn = -unmapf(mb);
  float y  = 1.0f / mx;   // correctly-rounded IEEE reciprocal

  // ---- staging: 1320 groups of 4 elems; aligned quad load + shfl for the -1 halo elem ----
  const int lane = tid & 63;
  #pragma unroll
  for (int it = 0; it < 6; ++it) {
    int e = it * 256 + tid;                 // 0..1535; valid < 1320
    bool ein = e < 1320;
    int lc = e / 330;
    int r  = e - lc * 330;
    int lh = r / 33;
    int lg = r - lh * 33;
    int c = c0 - 1 + lc, h = h0 - 1 + lh;
    bool chok = ein & ((unsigned)c < 16u) & ((unsigned)h < 256u);
    int chbase = ((nbase + c) << 16) + (h << 8);
    int wq = w0 + 4 * lg;                   // aligned quad start (group covers w = wq-1..wq+2)
    bool qok = chok & (wq < 256);
    float4 vb = float4{0.f, 0.f, 0.f, 0.f};
    if (qok) vb = *(const float4*)&x[chbase + wq];
    float pe = __shfl_up(vb.w, 1);          // prev group's quad.w == x[wq-1]
    if ((lg == 0) | (lane == 0)) {
      int wm = wq - 1;
      pe = (chok & (wm >= 0)) ? x[chbase + wm] : 0.0f;   // wm<256 always (wq<=128+...)
    }
    float xv[4] = {pe, vb.x, vb.y, vb.z};
    uint32_t qu[4];
    #pragma unroll
    for (int j = 0; j < 4; ++j) {
      int q = quant_q(xv[j], mn, mx, y);
      qu[j] = (uint32_t)(q > 7 ? 7 : q);    // JAX gather clamps OOB index for tap lookups
    }
    if (ein) {
      uint32_t b01 = __builtin_amdgcn_perm(qu[1], qu[0], 0x0c0c0400u);
      uint32_t b23 = __builtin_amdgcn_perm(qu[3], qu[2], 0x04000c0cu);
      int ro = lc * 10 + lh;
      *(float4*)&xs[ro * 132 + 4 * lg] = float4{xv[0], xv[1], xv[2], xv[3]};
      qls[ro * 33 + lg] = b01 | b23;
    }
  }
  __syncthreads();

  float wf[27];
  #pragma unroll
  for (int i = 0; i < 27; ++i) wf[i] = sfil[i];   // uniform -> scalar regs

  const int tw = tid & 31, th = tid >> 5;
  const uint32_t SELK[4] = {0x03020100u, 0x04030201u, 0x05040302u, 0x06050403u};

  for (int c = 0; c < 2; ++c) {
    int xbase = (c * 10 + th) * 132 + 4 * tw;
    int qbase = (c * 10 + th) * 33 + tw;

    // center q-bytes (clamped) -> per-output table rows
    int qc = qbase + 11 * 33;
    uint32_t Qc0 = qls[qc], Qc1 = qls[qc + 1];
    uint32_t q4 = __builtin_amdgcn_perm(Qc1, Qc0, 0x04030201u);
    uint32_t rlo[4], rhi[4]; float rs4[4], rc4[4];
    #pragma unroll
    for (int k = 0; k < 4; ++k) {
      uint32_t qk = (q4 >> (8 * k)) & 0xffu;
      uint4 T = tbl[qk];
      rlo[k] = T.x; rhi[k] = T.y;
      rs4[k] = __uint_as_float(T.z); rc4[k] = __uint_as_float(T.w);
    }

    float acc1[4] = {0.f, 0.f, 0.f, 0.f};
    float acc2[4] = {0.f, 0.f, 0.f, 0.f};
    float4 cxA; float2 cxB;   // center-row clean x (captured at dc=1,di=1)
    #pragma unroll
    for (int dc = 0; dc < 3; ++dc) {
      #pragma unroll
      for (int di = 0; di < 3; ++di) {
        int xo = xbase + (dc * 10 + di) * 132;
        float4 A = *(const float4*)&xs[xo];
        float2 B = *(const float2*)&xs[xo + 4];
        if (dc == 1 && di == 1) { cxA = A; cxB = B; }
        int qo = qbase + (dc * 10 + di) * 33;
        uint32_t Q0 = qls[qo], Q1 = qls[qo + 1];
        float xw[6] = {A.x, A.y, A.z, A.w, B.x, B.y};
        const float* wr = &wf[dc * 9 + di * 3];
        #pragma unroll
        for (int k = 0; k < 4; ++k) {
          uint32_t sel = __builtin_amdgcn_perm(Q1, Q0, SELK[k]);     // 3 q-bytes
          uint32_t bb  = __builtin_amdgcn_perm(rhi[k], rlo[k], sel); // 3 table bytes
          float b0 = (float)(bb & 0xffu);          // v_cvt_f32_ubyte0
          float b1 = (float)((bb >> 8) & 0xffu);   // v_cvt_f32_ubyte1
          float b2 = (float)((bb >> 16) & 0xffu);  // v_cvt_f32_ubyte2
          float p0 = wr[0] * xw[k];
          float p1 = wr[1] * xw[k + 1];
          float p2 = wr[2] * xw[k + 2];
          acc2[k] += p0 + p1 + p2;
          acc1[k] = __builtin_fmaf(p0, b0, acc1[k]);
          acc1[k] = __builtin_fmaf(p1, b1, acc1[k]);
          acc1[k] = __builtin_fmaf(p2, b2, acc1[k]);
        }
      }
    }

    // recompute exact unclamped q for the 4 center elements (for idx out + q==8 mask)
    float cx[4] = {cxA.y, cxA.z, cxA.w, cxB.x};
    int qt[4];
    #pragma unroll
    for (int k = 0; k < 4; ++k) qt[k] = quant_q(cx[k], mn, mx, y);

    int gbase = ((nbase + c0 + c) << 16) + ((h0 + th) << 8) + (w0 + 4 * tw);
    float4 o;
    o.x = qt[0] > 7 ? 0.0f : __builtin_fmaf(rs4[0], acc1[0], rc4[0] * acc2[0]);
    o.y = qt[1] > 7 ? 0.0f : __builtin_fmaf(rs4[1], acc1[1], rc4[1] * acc2[1]);
    o.z = qt[2] > 7 ? 0.0f : __builtin_fmaf(rs4[2], acc1[2], rc4[2] * acc2[2]);
    o.w = qt[3] > 7 ? 0.0f : __builtin_fmaf(rs4[3], acc1[3], rc4[3] * acc2[3]);
    *(float4*)&out[gbase] = o;
    // idx chunk is misaligned by 91 dwords; middle pair is 8B-aligned
    out_idx[gbase + 0] = (float)qt[0];
    *(float2*)&out_idx[gbase + 1] = float2{(float)qt[1], (float)qt[2]};
    out_idx[gbase + 3] = (float)qt[3];
  }
}

extern "C" void kernel_launch(void* const* d_in, const int* in_sizes, int n_in,
                              void* d_out, int out_size, void* d_ws, size_t ws_size,
                              hipStream_t stream) {
  const float* x    = (const float*)d_in[0];
  const float* co   = (const float*)d_in[1];
  const float* sfil = (const float*)d_in[2];
  float* out = (float*)d_out;
  uint32_t* wsu = (uint32_t*)d_ws;
  int nx = in_sizes[0];  // 8*16*256*256

  int n4 = nx / 4, ntail = nx - 4 * n4;

  float* out_co  = out + nx;
  float* out_sf  = out + nx + 64;
  float* out_idx = out + nx + 64 + 27;

  // zero the 32 spread atomic-max slots (one 128-B memset node)
  hipMemsetAsync(wsu + 64, 0, 128, stream);

  k_minmax<<<512, 256, 0, stream>>>(x, n4, ntail, co, sfil, wsu, out_co, out_sf);
  k_conv<<<4096, 256, 0, stream>>>(x, sfil, wsu, out, out_idx);
}

// Round 8
// 135.060 us; speedup vs baseline: 1.3511x; 1.0104x over previous
//
#include <hip/hip_runtime.h>
#include <stdint.h>

// monotone order-preserving float<->uint mapping (works for all signs)
__device__ __forceinline__ uint32_t mapf(float f) {
  uint32_t u = __float_as_uint(f);
  return (u & 0x80000000u) ? ~u : (u | 0x80000000u);
}
__device__ __forceinline__ float unmapf(uint32_t m) {
  return (m & 0x80000000u) ? __uint_as_float(m & 0x7FFFFFFFu) : __uint_as_float(~m);
}

// ws dwords: [8..39]=table: 8 x (rlo,rhi,scale,offset)
//            [64..79]=slotA (mapped max, 16-way spread)  [80..95]=slotB (mapped -min)

// ---------------- kernel 1: global min/max (spread atomics),
//                  block 0 also builds byte table + copies small outputs ----------------
__global__ __launch_bounds__(256) void k_minmax(const float* __restrict__ x, int n4, int ntail,
                                                const float* __restrict__ co, const float* __restrict__ sfil,
                                                uint32_t* __restrict__ wsu,
                                                float* __restrict__ out_co, float* __restrict__ out_sf) {
  __shared__ float smn[256], smx[256];
  int tid = threadIdx.x;
  float mn = 3.0e38f, mx = -3.0e38f;
  const float4* x4 = (const float4*)x;
  int stride = gridDim.x * blockDim.x;
  #pragma unroll 4
  for (int i = blockIdx.x * blockDim.x + tid; i < n4; i += stride) {
    float4 v = x4[i];
    mn = fminf(mn, fminf(fminf(v.x, v.y), fminf(v.z, v.w)));
    mx = fmaxf(mx, fmaxf(fmaxf(v.x, v.y), fmaxf(v.z, v.w)));
  }
  if (blockIdx.x == 0 && tid == 0) {
    for (int i = 4 * n4; i < 4 * n4 + ntail; ++i) { mn = fminf(mn, x[i]); mx = fmaxf(mx, x[i]); }
  }
  smn[tid] = mn; smx[tid] = mx;
  __syncthreads();
  for (int s = 128; s > 0; s >>= 1) {
    if (tid < s) { smn[tid] = fminf(smn[tid], smn[tid + s]); smx[tid] = fmaxf(smx[tid], smx[tid + s]); }
    __syncthreads();
  }
  if (tid == 0) {
    int slot = blockIdx.x & 15;
    atomicMax(&wsu[64 + slot], mapf(smx[0]));    // max
    atomicMax(&wsu[80 + slot], mapf(-smn[0]));   // min via max of negation (exact)
  }
  if (blockIdx.x == 0) {
    if (tid < 8) {   // per-row byte quantization of co_matrix
      const float* r = co + tid * 8;
      float rmn = r[0], rmx = r[0];
      #pragma unroll
      for (int j = 1; j < 8; ++j) { rmn = fminf(rmn, r[j]); rmx = fmaxf(rmx, r[j]); }
      float rs = (rmx - rmn) * (1.0f / 255.0f);
      if (rs < 1e-30f) rs = 1.0f;
      uint32_t d0 = 0, d1 = 0;
      #pragma unroll
      for (int j = 0; j < 8; ++j) {
        int b = (int)lrintf((r[j] - rmn) / rs);
        b = b < 0 ? 0 : (b > 255 ? 255 : b);
        if (j < 4) d0 |= ((uint32_t)b) << (8 * j);
        else       d1 |= ((uint32_t)b) << (8 * (j - 4));
      }
      wsu[8 + 4 * tid + 0] = d0;
      wsu[8 + 4 * tid + 1] = d1;
      wsu[8 + 4 * tid + 2] = __float_as_uint(rs);
      wsu[8 + 4 * tid + 3] = __float_as_uint(rmn);
    }
    if (tid < 64) out_co[tid] = co[tid];
    if (tid < 27) out_sf[tid] = sfil[tid];
  }
}

// 5-op scaled Markstein: d8 = 8 * RN((xv-mn)/mx), bit-exact.
// y8 = 8*RN(1/mx), mx8 = mx/8 (both exact pow2 scalings; RN commutes with *8).
__device__ __forceinline__ float quant_d8(float xv, float mn, float mx8, float y8) {
  float s   = xv - mn;
  float t08 = s * y8;
  float r0  = __builtin_fmaf(-mx8, t08, s);
  return __builtin_fmaf(r0, y8, t08);
}

// ---------------- kernel 2: fused quantize + selected 27-tap stencil ----------------
// tile: 2 c x 8 h x 128 w; 256 threads = 32(w) x 8(h); 4 w-outputs/thread, 2 c-iters
// LDS 26.6 KB -> 6 blocks/CU
__global__ __launch_bounds__(256) void k_conv(const float* __restrict__ x, const float* __restrict__ sfil,
                                              const uint32_t* __restrict__ wsu,
                                              float* __restrict__ out, float* __restrict__ out_idx) {
  __shared__ __align__(16) float    xs[5280];    // 4 planes x 10 rows x 132
  __shared__ __align__(16) uint32_t qls[1320];   // 4 x 10 x 33 (4 clamped q-bytes per dword)
  __shared__ __align__(16) uint4    tbl[8];      // rlo, rhi, scale, offset per q0

  int tid = threadIdx.x;
  int b = blockIdx.x;
  int wt = b & 1, ht = (b >> 1) & 31, ct = (b >> 6) & 7, n = b >> 9;
  int c0 = ct * 2, h0 = ht * 8, w0 = wt * 128;
  int nbase = n * 16;

  if (tid < 8) tbl[tid] = ((const uint4*)(wsu + 8))[tid];

  // reduce the 16+16 spread slots (uniform scalar loads)
  uint32_t ma = 0u, mb = 0u;
  #pragma unroll
  for (int i = 0; i < 16; ++i) {
    uint32_t a = wsu[64 + i], bq = wsu[80 + i];
    ma = ma > a ? ma : a;
    mb = mb > bq ? mb : bq;
  }
  float mx = unmapf(ma);
  float mn = -unmapf(mb);
  float y   = 1.0f / mx;     // correctly-rounded IEEE reciprocal
  float y8  = y * 8.0f;      // exact
  float mx8 = mx * 0.125f;   // exact

  const int tx = tid & 31, ty = tid >> 5;

  // ---- staging: 40 rows x 32 groups (division-free) + 40-group tail column ----
  {
    const int xoff = 4 * tx;               // dword offset within row
    #pragma unroll
    for (int it = 0; it < 5; ++it) {
      int rr = ty + 8 * it;                // 0..39
      int lc = (rr * 13) >> 7;             // rr/10 for rr<40
      int lh = rr - 10 * lc;
      int c = c0 - 1 + lc, h = h0 - 1 + lh;
      bool chok = ((unsigned)c < 16u) & ((unsigned)h < 256u);
      int chbase = ((nbase + c) << 16) + (h << 8);
      int wq = w0 + 4 * tx;                // <=252 always: quad load never OOB in w
      float4 vb = float4{0.f, 0.f, 0.f, 0.f};
      if (chok) vb = *(const float4*)&x[chbase + wq];
      float pe = __shfl_up(vb.w, 1);       // prev group's quad.w == x[wq-1]
      if (tx == 0) {
        int wm = wq - 1;
        pe = (chok & (wm >= 0)) ? x[chbase + wm] : 0.0f;
      }
      float xv[4] = {pe, vb.x, vb.y, vb.z};
      uint32_t qu[4];
      #pragma unroll
      for (int j = 0; j < 4; ++j) {
        int q = (int)quant_d8(xv[j], mn, mx8, y8);
        qu[j] = min((uint32_t)q, 7u);      // JAX gather clamps OOB index for tap lookups
      }
      uint32_t b01 = __builtin_amdgcn_perm(qu[1], qu[0], 0x0c0c0400u);
      uint32_t b23 = __builtin_amdgcn_perm(qu[3], qu[2], 0x04000c0cu);
      *(float4*)&xs[rr * 132 + xoff] = float4{xv[0], xv[1], xv[2], xv[3]};
      qls[rr * 33 + tx] = b01 | b23;
    }
    if (tid < 40) {                        // tail: lg = 32 for each of the 40 rows
      int rr = tid;
      int lc = (rr * 13) >> 7;
      int lh = rr - 10 * lc;
      int c = c0 - 1 + lc, h = h0 - 1 + lh;
      bool chok = ((unsigned)c < 16u) & ((unsigned)h < 256u);
      int chbase = ((nbase + c) << 16) + (h << 8);
      int wq = w0 + 128;                   // may be 256 (OOB) when w0==128
      float4 vb = float4{0.f, 0.f, 0.f, 0.f};
      if (chok & (wq < 256)) vb = *(const float4*)&x[chbase + wq];
      float pe = chok ? x[chbase + wq - 1] : 0.0f;   // wq-1 <= 255 always
      float xv[4] = {pe, vb.x, vb.y, vb.z};
      uint32_t qu[4];
      #pragma unroll
      for (int j = 0; j < 4; ++j) {
        int q = (int)quant_d8(xv[j], mn, mx8, y8);
        qu[j] = min((uint32_t)q, 7u);
      }
      uint32_t b01 = __builtin_amdgcn_perm(qu[1], qu[0], 0x0c0c0400u);
      uint32_t b23 = __builtin_amdgcn_perm(qu[3], qu[2], 0x04000c0cu);
      *(float4*)&xs[rr * 132 + 128] = float4{xv[0], xv[1], xv[2], xv[3]};
      qls[rr * 33 + 32] = b01 | b23;
    }
  }
  __syncthreads();

  float wf[27];
  #pragma unroll
  for (int i = 0; i < 27; ++i) wf[i] = sfil[i];   // uniform -> scalar regs

  const int tw = tx, th = ty;
  const uint32_t SELK[4] = {0x03020100u, 0x04030201u, 0x05040302u, 0x06050403u};

  for (int c = 0; c < 2; ++c) {
    int xbase = (c * 10 + th) * 132 + 4 * tw;
    int qbase = (c * 10 + th) * 33 + tw;

    // center q-bytes (clamped) -> per-output table rows
    int qc = qbase + 11 * 33;
    uint32_t Qc0 = qls[qc], Qc1 = qls[qc + 1];
    uint32_t q4 = __builtin_amdgcn_perm(Qc1, Qc0, 0x04030201u);
    uint32_t rlo[4], rhi[4]; float rs4[4], rc4[4];
    #pragma unroll
    for (int k = 0; k < 4; ++k) {
      uint32_t qk = (q4 >> (8 * k)) & 0xffu;
      uint4 T = tbl[qk];
      rlo[k] = T.x; rhi[k] = T.y;
      rs4[k] = __uint_as_float(T.z); rc4[k] = __uint_as_float(T.w);
    }

    float acc1[4] = {0.f, 0.f, 0.f, 0.f};
    float acc2[4] = {0.f, 0.f, 0.f, 0.f};
    float4 cxA; float2 cxB;   // center-row clean x (captured at dc=1,di=1)
    #pragma unroll
    for (int dc = 0; dc < 3; ++dc) {
      #pragma unroll
      for (int di = 0; di < 3; ++di) {
        int xo = xbase + (dc * 10 + di) * 132;
        float4 A = *(const float4*)&xs[xo];
        float2 B = *(const float2*)&xs[xo + 4];
        if (dc == 1 && di == 1) { cxA = A; cxB = B; }
        int qo = qbase + (dc * 10 + di) * 33;
        uint32_t Q0 = qls[qo], Q1 = qls[qo + 1];
        float xw[6] = {A.x, A.y, A.z, A.w, B.x, B.y};
        const float* wr = &wf[dc * 9 + di * 3];
        #pragma unroll
        for (int k = 0; k < 4; ++k) {
          uint32_t sel = __builtin_amdgcn_perm(Q1, Q0, SELK[k]);     // 3 q-bytes
          uint32_t bb  = __builtin_amdgcn_perm(rhi[k], rlo[k], sel); // 3 table bytes
          float b0 = (float)(bb & 0xffu);          // v_cvt_f32_ubyte0
          float b1 = (float)((bb >> 8) & 0xffu);   // v_cvt_f32_ubyte1
          float b2 = (float)((bb >> 16) & 0xffu);  // v_cvt_f32_ubyte2
          float p0 = wr[0] * xw[k];
          float p1 = wr[1] * xw[k + 1];
          float p2 = wr[2] * xw[k + 2];
          acc2[k] += p0 + p1 + p2;
          acc1[k] = __builtin_fmaf(p0, b0, acc1[k]);
          acc1[k] = __builtin_fmaf(p1, b1, acc1[k]);
          acc1[k] = __builtin_fmaf(p2, b2, acc1[k]);
        }
      }
    }

    // epilogue: d8 per center element; idx = trunc(d8) (8.0 falls out naturally)
    float cx[4] = {cxA.y, cxA.z, cxA.w, cxB.x};
    float idxf[4]; float vals[4];
    #pragma unroll
    for (int k = 0; k < 4; ++k) {
      float d8 = quant_d8(cx[k], mn, mx8, y8);
      idxf[k] = truncf(d8);
      float v = __builtin_fmaf(rs4[k], acc1[k], rc4[k] * acc2[k]);
      vals[k] = (d8 >= 8.0f) ? 0.0f : v;   // idx==8 matches no mask channel
    }

    int gbase = ((nbase + c0 + c) << 16) + ((h0 + th) << 8) + (w0 + 4 * tw);
    *(float4*)&out[gbase] = float4{vals[0], vals[1], vals[2], vals[3]};
    // idx chunk is misaligned by 91 dwords; middle pair is 8B-aligned
    out_idx[gbase + 0] = idxf[0];
    *(float2*)&out_idx[gbase + 1] = float2{idxf[1], idxf[2]};
    out_idx[gbase + 3] = idxf[3];
  }
}

extern "C" void kernel_launch(void* const* d_in, const int* in_sizes, int n_in,
                              void* d_out, int out_size, void* d_ws, size_t ws_size,
                              hipStream_t stream) {
  const float* x    = (const float*)d_in[0];
  const float* co   = (const float*)d_in[1];
  const float* sfil = (const float*)d_in[2];
  float* out = (float*)d_out;
  uint32_t* wsu = (uint32_t*)d_ws;
  int nx = in_sizes[0];  // 8*16*256*256

  int n4 = nx / 4, ntail = nx - 4 * n4;

  float* out_co  = out + nx;
  float* out_sf  = out + nx + 64;
  float* out_idx = out + nx + 64 + 27;

  // zero the 32 spread atomic-max slots (one 128-B memset node)
  hipMemsetAsync(wsu + 64, 0, 128, stream);

  k_minmax<<<512, 256, 0, stream>>>(x, n4, ntail, co, sfil, wsu, out_co, out_sf);
  k_conv<<<4096, 256, 0, stream>>>(x, sfil, wsu, out, out_idx);
}